// Round 1
// baseline (356.334 us; speedup 1.0000x reference)
//
#include <hip/hip_runtime.h>
#include <math.h>

#define HIDDEN 64

__global__ __launch_bounds__(256) void nerf_render_kernel(
    const float* __restrict__ rays_o, const float* __restrict__ rays_d,
    const float* __restrict__ W1, const float* __restrict__ b1,
    const float* __restrict__ W2, const float* __restrict__ b2,
    const float* __restrict__ t_starts, const float* __restrict__ t_ends,
    const int* __restrict__ ray_indices,
    float* __restrict__ out, int n_rays, int n_samples)
{
    __shared__ float sW1[3 * HIDDEN];   // sW1[k*64+j] = W1[k][j]
    __shared__ float sb1[HIDDEN];
    __shared__ float sW2[HIDDEN];
    __shared__ float sb2;

    const int tid = threadIdx.x;
    // Cooperative load of MLP weights into LDS (once per block).
    for (int i = tid; i < 3 * HIDDEN; i += blockDim.x) sW1[i] = W1[i];
    if (tid < HIDDEN) {
        sb1[tid] = b1[tid];
        sW2[tid] = W2[tid];
    }
    if (tid == 0) sb2 = b2[0];
    __syncthreads();

    const int lane = tid & 63;
    const int ray  = (blockIdx.x * blockDim.x + tid) >> 6;   // one wave64 per ray
    if (ray >= n_rays) return;

    // --- segment bounds: searchsorted(ray_indices, ray) and (ray+1) ---
    // even lanes search target=ray, odd lanes target=ray+1; broadcast after.
    {
    }
    int target = ray + (lane & 1);
    int lo = 0, hi = n_samples;
    while (lo < hi) {
        int mid = (lo + hi) >> 1;
        if (ray_indices[mid] < target) lo = mid + 1; else hi = mid;
    }
    const int seg_start = __shfl(lo, 0, 64);
    const int seg_end   = __shfl(lo, 1, 64);

    // ray origin/direction (wave-uniform loads, served by cache)
    const float ox = rays_o[3 * ray + 0];
    const float oy = rays_o[3 * ray + 1];
    const float oz = rays_o[3 * ray + 2];
    const float dx = rays_d[3 * ray + 0];
    const float dy = rays_d[3 * ray + 1];
    const float dz = rays_d[3 * ray + 2];

    float carry     = 0.0f;   // per-ray cumulative sum of sigma*dt from prior passes
    float op_acc    = 0.0f;   // sum of weights (this lane's samples)
    float depth_acc = 0.0f;   // sum of weights * t_mid

    for (int base = seg_start; base < seg_end; base += 64) {
        const int i = base + lane;
        const bool valid = (i < seg_end);

        float tm = 0.0f, sval = 0.0f, alpha = 0.0f;
        if (valid) {
            const float ts = t_starts[i];
            const float te = t_ends[i];
            tm = 0.5f * (ts + te);
            const float dt = te - ts;

            const float px = fmaf(dx, tm, ox);
            const float py = fmaf(dy, tm, oy);
            const float pz = fmaf(dz, tm, oz);

            // MLP: h = relu(pos @ W1 + b1); z = h @ W2 + b2
            float acc0 = 0.0f, acc1 = 0.0f, acc2 = 0.0f, acc3 = 0.0f;
            #pragma unroll
            for (int j = 0; j < HIDDEN; j += 4) {
                float h0 = fmaf(px, sW1[j + 0],
                           fmaf(py, sW1[HIDDEN + j + 0],
                           fmaf(pz, sW1[2 * HIDDEN + j + 0], sb1[j + 0])));
                float h1 = fmaf(px, sW1[j + 1],
                           fmaf(py, sW1[HIDDEN + j + 1],
                           fmaf(pz, sW1[2 * HIDDEN + j + 1], sb1[j + 1])));
                float h2 = fmaf(px, sW1[j + 2],
                           fmaf(py, sW1[HIDDEN + j + 2],
                           fmaf(pz, sW1[2 * HIDDEN + j + 2], sb1[j + 2])));
                float h3 = fmaf(px, sW1[j + 3],
                           fmaf(py, sW1[HIDDEN + j + 3],
                           fmaf(pz, sW1[2 * HIDDEN + j + 3], sb1[j + 3])));
                h0 = fmaxf(h0, 0.0f);
                h1 = fmaxf(h1, 0.0f);
                h2 = fmaxf(h2, 0.0f);
                h3 = fmaxf(h3, 0.0f);
                acc0 = fmaf(h0, sW2[j + 0], acc0);
                acc1 = fmaf(h1, sW2[j + 1], acc1);
                acc2 = fmaf(h2, sW2[j + 2], acc2);
                acc3 = fmaf(h3, sW2[j + 3], acc3);
            }
            const float z = (acc0 + acc1) + (acc2 + acc3) + sb2;
            // stable softplus: log1p(exp(z))
            const float sigma = fmaxf(z, 0.0f) + log1pf(expf(-fabsf(z)));
            sval  = sigma * dt;
            alpha = 1.0f - expf(-sval);
        }

        // wave64 inclusive scan of sval
        float scan = sval;
        #pragma unroll
        for (int off = 1; off < 64; off <<= 1) {
            float n = __shfl_up(scan, off, 64);
            if (lane >= off) scan += n;
        }
        const float excl  = carry + (scan - sval);   // per-ray exclusive cumsum
        const float trans = expf(-excl);
        const float w     = valid ? trans * alpha : 0.0f;

        op_acc    += w;
        depth_acc += w * tm;
        carry     += __shfl(scan, 63, 64);  // pass total (invalid lanes contributed 0)
    }

    // wave64 butterfly reduction of op_acc / depth_acc
    #pragma unroll
    for (int off = 32; off > 0; off >>= 1) {
        op_acc    += __shfl_down(op_acc, off, 64);
        depth_acc += __shfl_down(depth_acc, off, 64);
    }

    if (lane == 0) {
        const float tiny = 1.17549435e-38f;
        out[2 * ray + 0] = op_acc;
        out[2 * ray + 1] = depth_acc / fmaxf(op_acc, tiny);
    }
}

extern "C" void kernel_launch(void* const* d_in, const int* in_sizes, int n_in,
                              void* d_out, int out_size, void* d_ws, size_t ws_size,
                              hipStream_t stream) {
    const float* rays_o      = (const float*)d_in[0];
    const float* rays_d      = (const float*)d_in[1];
    const float* W1          = (const float*)d_in[2];
    const float* b1          = (const float*)d_in[3];
    const float* W2          = (const float*)d_in[4];
    const float* b2          = (const float*)d_in[5];
    const float* t_starts    = (const float*)d_in[6];
    const float* t_ends      = (const float*)d_in[7];
    const int*   ray_indices = (const int*)d_in[8];

    const int n_rays    = in_sizes[0] / 3;   // rays_o is [n_rays, 3]
    const int n_samples = in_sizes[6];       // t_starts is [S]

    float* out = (float*)d_out;

    const int block = 256;                         // 4 waves per block
    const int waves_per_block = block / 64;
    const int grid = (n_rays + waves_per_block - 1) / waves_per_block;

    nerf_render_kernel<<<grid, block, 0, stream>>>(
        rays_o, rays_d, W1, b1, W2, b2, t_starts, t_ends, ray_indices,
        out, n_rays, n_samples);
}

// Round 2
// 155.522 us; speedup vs baseline: 2.2912x; 2.2912x over previous
//
#include <hip/hip_runtime.h>
#include <math.h>

#define HIDDEN 64

__global__ __launch_bounds__(256, 4) void nerf_render_kernel(
    const float* __restrict__ rays_o, const float* __restrict__ rays_d,
    const float* __restrict__ W1, const float* __restrict__ b1,
    const float* __restrict__ W2, const float* __restrict__ b2,
    const float* __restrict__ t_starts, const float* __restrict__ t_ends,
    const int* __restrict__ ray_indices,
    float* __restrict__ out, int n_rays, int n_samples)
{
    // Packed weights: sW[j] = {W1[0][j], W1[1][j], W1[2][j], b1[j]}  (one b128/unit)
    __shared__ float4 sW[HIDDEN];
    __shared__ float4 sW2v[HIDDEN / 4];
    __shared__ float  sb2;

    const int tid = threadIdx.x;
    if (tid < HIDDEN) {
        sW[tid] = make_float4(W1[tid], W1[HIDDEN + tid], W1[2 * HIDDEN + tid], b1[tid]);
    }
    if (tid < HIDDEN / 4) {
        sW2v[tid] = make_float4(W2[4 * tid], W2[4 * tid + 1], W2[4 * tid + 2], W2[4 * tid + 3]);
    }
    if (tid == 0) sb2 = b2[0];
    __syncthreads();

    const int lane = tid & 63;
    const int ray  = (blockIdx.x * blockDim.x + tid) >> 6;   // one wave64 per ray
    if (ray >= n_rays) return;

    // segment bounds: lane0 searches `ray`, lane1 searches `ray+1`; broadcast.
    int target = ray + (lane & 1);
    int lo = 0, hi = n_samples;
    while (lo < hi) {
        int mid = (lo + hi) >> 1;
        if (ray_indices[mid] < target) lo = mid + 1; else hi = mid;
    }
    const int seg_start = __shfl(lo, 0, 64);
    const int seg_end   = __shfl(lo, 1, 64);
    if (seg_start >= seg_end) {
        if (lane == 0) { out[2 * ray] = 0.0f; out[2 * ray + 1] = 0.0f; }
        return;
    }

    const float ox = rays_o[3 * ray + 0];
    const float oy = rays_o[3 * ray + 1];
    const float oz = rays_o[3 * ray + 2];
    const float dx = rays_d[3 * ray + 0];
    const float dy = rays_d[3 * ray + 1];
    const float dz = rays_d[3 * ray + 2];

    float carry     = 0.0f;
    float op_acc    = 0.0f;
    float depth_acc = 0.0f;

    for (int base = seg_start; base < seg_end; base += 64) {
        const int  i     = base + lane;
        const bool valid = (i < seg_end);
        const int  ii    = valid ? i : (seg_end - 1);   // clamped: no exec divergence

        const float ts = t_starts[ii];
        const float te = t_ends[ii];
        const float tm = 0.5f * (ts + te);
        const float dt = te - ts;

        const float px = fmaf(dx, tm, ox);
        const float py = fmaf(dy, tm, oy);
        const float pz = fmaf(dz, tm, oz);

        // MLP: z = relu(pos@W1 + b1) @ W2 + b2
        float acc0 = 0.0f, acc1 = 0.0f, acc2 = 0.0f, acc3 = 0.0f;
        #pragma unroll 2
        for (int j4 = 0; j4 < HIDDEN / 4; ++j4) {
            const float4 w2 = sW2v[j4];
            const float4 wa = sW[4 * j4 + 0];
            const float4 wb = sW[4 * j4 + 1];
            const float4 wc = sW[4 * j4 + 2];
            const float4 wd = sW[4 * j4 + 3];
            float h0 = fmaf(px, wa.x, fmaf(py, wa.y, fmaf(pz, wa.z, wa.w)));
            float h1 = fmaf(px, wb.x, fmaf(py, wb.y, fmaf(pz, wb.z, wb.w)));
            float h2 = fmaf(px, wc.x, fmaf(py, wc.y, fmaf(pz, wc.z, wc.w)));
            float h3 = fmaf(px, wd.x, fmaf(py, wd.y, fmaf(pz, wd.z, wd.w)));
            acc0 = fmaf(fmaxf(h0, 0.0f), w2.x, acc0);
            acc1 = fmaf(fmaxf(h1, 0.0f), w2.y, acc1);
            acc2 = fmaf(fmaxf(h2, 0.0f), w2.z, acc2);
            acc3 = fmaf(fmaxf(h3, 0.0f), w2.w, acc3);
        }
        const float z = (acc0 + acc1) + (acc2 + acc3) + sb2;

        // stable softplus
        const float sigma = fmaxf(z, 0.0f) + log1pf(expf(-fabsf(z)));
        float sval  = sigma * dt;
        float alpha = 1.0f - expf(-sval);
        sval = valid ? sval : 0.0f;

        // wave64 inclusive scan of sval
        float scan = sval;
        #pragma unroll
        for (int off = 1; off < 64; off <<= 1) {
            float n = __shfl_up(scan, off, 64);
            if (lane >= off) scan += n;
        }
        const float excl  = carry + (scan - sval);
        const float trans = expf(-excl);
        const float w     = valid ? trans * alpha : 0.0f;

        op_acc    += w;
        depth_acc += w * tm;
        carry     += __shfl(scan, 63, 64);
    }

    // wave64 butterfly reduction
    #pragma unroll
    for (int off = 32; off > 0; off >>= 1) {
        op_acc    += __shfl_down(op_acc, off, 64);
        depth_acc += __shfl_down(depth_acc, off, 64);
    }

    if (lane == 0) {
        const float tiny = 1.17549435e-38f;
        out[2 * ray + 0] = op_acc;
        out[2 * ray + 1] = depth_acc / fmaxf(op_acc, tiny);
    }
}

extern "C" void kernel_launch(void* const* d_in, const int* in_sizes, int n_in,
                              void* d_out, int out_size, void* d_ws, size_t ws_size,
                              hipStream_t stream) {
    const float* rays_o      = (const float*)d_in[0];
    const float* rays_d      = (const float*)d_in[1];
    const float* W1          = (const float*)d_in[2];
    const float* b1          = (const float*)d_in[3];
    const float* W2          = (const float*)d_in[4];
    const float* b2          = (const float*)d_in[5];
    const float* t_starts    = (const float*)d_in[6];
    const float* t_ends      = (const float*)d_in[7];
    const int*   ray_indices = (const int*)d_in[8];

    const int n_rays    = in_sizes[0] / 3;
    const int n_samples = in_sizes[6];

    float* out = (float*)d_out;

    const int block = 256;                      // 4 waves/block
    const int grid  = (n_rays * 64 + block - 1) / block;

    nerf_render_kernel<<<grid, block, 0, stream>>>(
        rays_o, rays_d, W1, b1, W2, b2, t_starts, t_ends, ray_indices,
        out, n_rays, n_samples);
}